// Round 1
// 86.541 us; speedup vs baseline: 1.0992x; 1.0992x over previous
//
#include <hip/hip_runtime.h>
#include <math.h>

#define BATCH 256
#define DIMZ  64
#define NSAMP 32
#define JB    32   // j values per block; 8 jj-groups x 4 per thread

__global__ __launch_bounds__(256) void lpo_kl_kernel(
    const float* __restrict__ prior_mean,
    const float* __restrict__ prior_logvar,
    const float* __restrict__ post_mean,
    const float* __restrict__ post_logvar,
    const float* __restrict__ eps,
    float* __restrict__ out)
{
    constexpr float LOG_2PI = 1.8378770664093453f;
    constexpr float VAR_EPS = 1e-4f;
    constexpr float LOG2E   = 1.4426950408889634f;
    constexpr float LN2     = 0.6931471805599453f;
    constexpr float LOG_B   = 5.545177444479562f;   // ln(256)

    // Per-i quadratic coefficients in log2 domain:
    //   log2 p_i(z) = A_i + B_i*z - C_i*z^2
    // with C = LOG2E/den, B = 2*m*C, A = LOG2E*(-.5*LOG_2PI - .5*lv) - m*m*C
    __shared__ __align__(16) float A_s[BATCH];
    __shared__ __align__(16) float B_s[BATCH];
    __shared__ __align__(16) float C_s[BATCH];
    __shared__ float m_s[BATCH];
    __shared__ float sg_s[BATCH];
    __shared__ float wred[4];

    const int tid = threadIdx.x;
    const int d   = blockIdx.x & (DIMZ - 1);
    const int j0  = (blockIdx.x >> 6) * JB;

    // Build the per-d posterior table (one entry per batch index i).
    {
        const int i   = tid;
        float m   = post_mean[i * DIMZ + d];
        float lv  = post_logvar[i * DIMZ + d];
        float den = 2.0f * __expf(lv) + VAR_EPS;
        float C   = LOG2E / den;
        float B   = 2.0f * m * C;
        float A   = LOG2E * (-0.5f * LOG_2PI - 0.5f * lv) - m * m * C;
        A_s[i]  = A;
        B_s[i]  = B;
        C_s[i]  = C;
        m_s[i]  = m;
        sg_s[i] = __expf(0.5f * lv);
    }
    __syncthreads();

    const int s  = tid & (NSAMP - 1);
    const int jj = tid >> 5;                 // 0..7

    // Each thread owns 4 outputs: j = j0 + jj + 8k, same (d, s).
    float z[4], nz2[4];
    #pragma unroll
    for (int k = 0; k < 4; ++k) {
        const int j = j0 + jj + 8 * k;
        z[k]   = m_s[j] + eps[(j * DIMZ + d) * NSAMP + s] * sg_s[j];
        nz2[k] = -(z[k] * z[k]);
    }

    // sum_i 2^{log2 p_i(z_k)} for each of the 4 z's.
    // One 48B table read now feeds 16 exp2 terms (4 i-slots x 4 outputs).
    float acc[4][4] = {};   // [i-slot][k] -- all indices compile-time after unroll
    #pragma unroll 2
    for (int i = 0; i < BATCH; i += 4) {
        const float4 Av = *(const float4*)(A_s + i);
        const float4 Bv = *(const float4*)(B_s + i);
        const float4 Cv = *(const float4*)(C_s + i);
        #pragma unroll
        for (int k = 0; k < 4; ++k) {
            acc[0][k] += __builtin_amdgcn_exp2f(
                __builtin_fmaf(Cv.x, nz2[k], __builtin_fmaf(Bv.x, z[k], Av.x)));
            acc[1][k] += __builtin_amdgcn_exp2f(
                __builtin_fmaf(Cv.y, nz2[k], __builtin_fmaf(Bv.y, z[k], Av.y)));
            acc[2][k] += __builtin_amdgcn_exp2f(
                __builtin_fmaf(Cv.z, nz2[k], __builtin_fmaf(Bv.z, z[k], Av.z)));
            acc[3][k] += __builtin_amdgcn_exp2f(
                __builtin_fmaf(Cv.w, nz2[k], __builtin_fmaf(Bv.w, z[k], Av.w)));
        }
    }

    // Epilogue: per-output logsumexp, prior log-density, gap; fold the 4
    // equally-weighted outputs into one per-thread contribution.
    float contrib = 0.0f;
    #pragma unroll
    for (int k = 0; k < 4; ++k) {
        const int j = j0 + jj + 8 * k;
        const float sum = (acc[0][k] + acc[1][k]) + (acc[2][k] + acc[3][k]);
        const float lse_nat = LN2 * __builtin_amdgcn_logf(sum) - LOG_B;

        const float pm   = prior_mean[j * DIMZ + d];
        const float plv  = prior_logvar[j * DIMZ + d];
        const float pden = 2.0f * __expf(plv) + VAR_EPS;
        const float dz   = z[k] - pm;
        const float logp_prior = -0.5f * LOG_2PI - 0.5f * plv - dz * dz / pden;

        contrib += lse_nat - logp_prior;
    }
    contrib *= 1.0f / (BATCH * NSAMP);

    // wave reduce (width 64), then cross-wave via LDS, one atomic per block
    for (int off = 32; off > 0; off >>= 1)
        contrib += __shfl_down(contrib, off);
    if ((tid & 63) == 0) wred[tid >> 6] = contrib;
    __syncthreads();
    if (tid == 0)
        atomicAdd(out, (wred[0] + wred[1]) + (wred[2] + wred[3]));
}

extern "C" void kernel_launch(void* const* d_in, const int* in_sizes, int n_in,
                              void* d_out, int out_size, void* d_ws, size_t ws_size,
                              hipStream_t stream) {
    const float* prior_mean   = (const float*)d_in[0];
    const float* prior_logvar = (const float*)d_in[1];
    const float* post_mean    = (const float*)d_in[2];
    const float* post_logvar  = (const float*)d_in[3];
    const float* eps          = (const float*)d_in[4];
    float* out = (float*)d_out;

    // harness poisons d_out with 0xAA before every timed launch
    hipMemsetAsync(out, 0, sizeof(float), stream);

    lpo_kl_kernel<<<dim3((BATCH / JB) * DIMZ), dim3(256), 0, stream>>>(
        prior_mean, prior_logvar, post_mean, post_logvar, eps, out);
}